// Round 1
// baseline (484.583 us; speedup 1.0000x reference)
//
#include <hip/hip_runtime.h>
#include <math.h>

// Problem constants
#define DD 300
#define BB 256
#define LL_TEXT 512
#define LA_ 8
#define LL_LEFT 64

// ws layout (float offsets)
#define WS_KV   0        // 300: Wk @ u  (u = w_mlp[:D])
#define WS_C0   300      // bk . u
#define WS_C1   301      // bq . u2
#define WS_G    302      // 300: Wx(Wx(Wx(Wq u2)))
#define WS_BKP  602      // 300: bk@Wproj + bproj
#define WS_M    1024     // 90000: Wk@Wproj
#define WS_MW   91024    // 256*300: softmax-weighted (w*emb) sums
#define WS_VS   167824   // 256*300: v_s vectors

// ---------------------------------------------------------------------------
// k_setup: grid 301 x 320.
//  blocks 0..299: row i of M = Wk @ Wproj
//  block 300:     kv, g-chain, bkp, c0, c1
// ---------------------------------------------------------------------------
__global__ __launch_bounds__(320) void k_setup(
    const float* __restrict__ Wx, const float* __restrict__ Wk,
    const float* __restrict__ bk, const float* __restrict__ Wq,
    const float* __restrict__ bq, const float* __restrict__ wmlp,
    const float* __restrict__ Wproj, const float* __restrict__ bproj,
    float* __restrict__ ws)
{
    const int j = threadIdx.x;
    if (blockIdx.x < 300) {
        const int i = blockIdx.x;
        if (j < 300) {
            float acc = 0.f;
            #pragma unroll 4
            for (int t = 0; t < 300; ++t)
                acc += Wk[i * 300 + t] * Wproj[t * 300 + j];
            ws[WS_M + i * 300 + j] = acc;
        }
        return;
    }
    // special block
    __shared__ float h[300];
    const float* u  = wmlp;
    const float* u2 = wmlp + 300;
    if (j < 300) {
        float a_kv = 0.f, a_h = 0.f, a_bkp = 0.f;
        #pragma unroll 4
        for (int t = 0; t < 300; ++t) {
            a_kv  += Wk[j * 300 + t] * u[t];
            a_h   += Wq[j * 300 + t] * u2[t];
            a_bkp += bk[t] * Wproj[t * 300 + j];
        }
        ws[WS_KV + j]  = a_kv;
        h[j]           = a_h;
        ws[WS_BKP + j] = a_bkp + bproj[j];
    }
    __syncthreads();
    for (int s = 0; s < 3; ++s) {
        float a = 0.f;
        if (j < 300) {
            #pragma unroll 4
            for (int t = 0; t < 300; ++t) a += Wx[j * 300 + t] * h[t];
        }
        __syncthreads();
        if (j < 300) h[j] = a;
        __syncthreads();
    }
    if (j < 300) ws[WS_G + j] = h[j];
    if (j == 0) {
        float c0 = 0.f;
        for (int t = 0; t < 300; ++t) c0 += bk[t] * u[t];
        ws[WS_C0] = c0;
    }
    if (j == 1) {
        float c1 = 0.f;
        for (int t = 0; t < 300; ++t) c1 += bq[t] * u2[t];
        ws[WS_C1] = c1;
    }
}

// ---------------------------------------------------------------------------
// k_main: grid 256 (one block per batch row) x 1024 (16 waves, 32 tokens each)
// Single pass over all embeddings: per-token score dot + exp-weighted
// accumulation (tanh bounds scores, no max-subtract needed) + v_s sum.
// ---------------------------------------------------------------------------
__global__ __launch_bounds__(1024) void k_main(
    const int* __restrict__ text, const int* __restrict__ aspect,
    const int* __restrict__ left, const float* __restrict__ embed,
    float* __restrict__ ws)
{
    const int b = blockIdx.x;
    const int t = threadIdx.x;
    const int wv = t >> 6;
    const int lane = t & 63;

    __shared__ int   toks[512];
    __shared__ int   atoks[8];
    __shared__ float red[512];
    __shared__ float accW[16 * 300];
    __shared__ float vsW[16 * 300];
    __shared__ float denomW[16];
    __shared__ int   cnts[3];   // mem_len, left_len, asp_len
    __shared__ float sc[4];     // mem_len_f, startf, endf, qb

    if (t < 3) cnts[t] = 0;
    __syncthreads();

    bool predm = false, predl = false, preda = false;
    if (t < 512) {
        int tk = text[b * 512 + t];
        toks[t] = tk;
        predm = (tk != 0);
    } else if (t < 576) {
        predl = (left[b * 64 + (t - 512)] != 0);
    } else if (t < 584) {
        int a = t - 576;
        int ak = aspect[b * 8 + a];
        atoks[a] = ak;
        preda = (ak != 0);
    }
    {
        unsigned long long m;
        m = __ballot(predm);
        if (lane == 0 && m) atomicAdd(&cnts[0], __popcll(m));
        m = __ballot(predl);
        if (lane == 0 && m) atomicAdd(&cnts[1], __popcll(m));
        m = __ballot(preda);
        if (lane == 0 && m) atomicAdd(&cnts[2], __popcll(m));
    }
    __syncthreads();

    // asp_e . g  -> qscal
    if (t < 300) {
        float s = 0.f;
        #pragma unroll
        for (int a = 0; a < 8; ++a)
            s += embed[(size_t)atoks[a] * 300 + t];
        float aspe = s / (float)cnts[2];
        red[t] = aspe * ws[WS_G + t];
    } else if (t < 512) {
        red[t] = 0.f;
    }
    __syncthreads();
    for (int s = 256; s > 0; s >>= 1) {
        if (t < s) red[t] += red[t + s];
        __syncthreads();
    }
    if (t == 0) {
        sc[0] = (float)cnts[0];
        sc[1] = (float)(cnts[1] - cnts[2]);
        sc[2] = (float)cnts[1];
        sc[3] = red[0] + ws[WS_C0] + ws[WS_C1];
    }
    __syncthreads();
    const float mem_len_f = sc[0];
    const float startf    = sc[1];
    const float endf      = sc[2];
    const float qb        = sc[3];

    float kvr[5];
    #pragma unroll
    for (int k = 0; k < 5; ++k) {
        int d = lane + 64 * k;
        kvr[k] = (d < 300) ? ws[WS_KV + d] : 0.f;
    }
    const bool d4ok = (lane < 44);

    float acc0 = 0.f, acc1 = 0.f, acc2 = 0.f, acc3 = 0.f, acc4 = 0.f;
    float vs0 = 0.f, vs1 = 0.f, vs2 = 0.f, vs3 = 0.f, vs4 = 0.f;
    float denom = 0.f;

    #pragma unroll 2
    for (int it = 0; it < 32; ++it) {
        const int l = wv * 32 + it;
        const int tok = toks[l];
        const float* row = embed + (size_t)tok * 300;
        float e0 = row[lane];
        float e1 = row[lane + 64];
        float e2 = row[lane + 128];
        float e3 = row[lane + 192];
        float e4 = d4ok ? row[lane + 256] : 0.f;

        const float idxf = (float)l;
        float lv = (idxf < startf) ? (startf - idxf)
                                   : ((idxf <= endf) ? 0.f : (idxf - endf));
        float wl = 1.f - lv / mem_len_f;
        wl = (idxf < mem_len_f) ? wl : 0.f;

        float pd = e0 * kvr[0] + e1 * kvr[1] + e2 * kvr[2] + e3 * kvr[3] + e4 * kvr[4];
        #pragma unroll
        for (int off = 32; off > 0; off >>= 1)
            pd += __shfl_xor(pd, off);

        const float sraw = tanhf(wl * pd + qb);
        const float p = expf(sraw);
        const float pw = p * wl;
        acc0 += pw * e0; acc1 += pw * e1; acc2 += pw * e2; acc3 += pw * e3; acc4 += pw * e4;
        vs0 += e0; vs1 += e1; vs2 += e2; vs3 += e3; vs4 += e4;
        denom += p;
    }

    // merge waves
    {
        float a[5] = {acc0, acc1, acc2, acc3, acc4};
        float v[5] = {vs0, vs1, vs2, vs3, vs4};
        #pragma unroll
        for (int k = 0; k < 5; ++k) {
            int d = lane + 64 * k;
            if (d < 300) {
                accW[wv * 300 + d] = a[k];
                vsW[wv * 300 + d]  = v[k];
            }
        }
    }
    if (lane == 0) denomW[wv] = denom;
    __syncthreads();

    if (t < 300) {
        float ds = 0.f;
        #pragma unroll
        for (int w = 0; w < 16; ++w) ds += denomW[w];
        float ms = 0.f, vs = 0.f;
        #pragma unroll
        for (int w = 0; w < 16; ++w) {
            ms += accW[w * 300 + t];
            vs += vsW[w * 300 + t];
        }
        ws[WS_MW + b * 300 + t] = ms / ds;
        ws[WS_VS + b * 300 + t] = vs / mem_len_f;
    }
}

// ---------------------------------------------------------------------------
// k_tail: grid 32 x 320 — 8 batch rows per block.
// vns = m_w@M + bkp + v_s ; vms = tanh(vns@Wm + bm) ; out = softmax(vms@Wd+bd)
// ---------------------------------------------------------------------------
__global__ __launch_bounds__(320) void k_tail(
    const float* __restrict__ Wm, const float* __restrict__ bm,
    const float* __restrict__ Wd, const float* __restrict__ bd,
    float* __restrict__ out, const float* __restrict__ ws)
{
    const int t = threadIdx.x;
    const int b0 = blockIdx.x * 8;

    __shared__ float mwS[2400];
    __shared__ float vsS[2400];
    __shared__ float vnsS[2400];
    __shared__ float vmsS[2400];
    __shared__ float lg[24];

    for (int i = t; i < 2400; i += 320) {
        mwS[i] = ws[WS_MW + b0 * 300 + i];
        vsS[i] = ws[WS_VS + b0 * 300 + i];
    }
    __syncthreads();

    if (t < 300) {
        float a[8] = {0.f, 0.f, 0.f, 0.f, 0.f, 0.f, 0.f, 0.f};
        #pragma unroll 2
        for (int i = 0; i < 300; ++i) {
            float mj = ws[WS_M + i * 300 + t];
            #pragma unroll
            for (int r = 0; r < 8; ++r) a[r] += mwS[r * 300 + i] * mj;
        }
        float bkp = ws[WS_BKP + t];
        #pragma unroll
        for (int r = 0; r < 8; ++r)
            vnsS[r * 300 + t] = a[r] + bkp + vsS[r * 300 + t];
    }
    __syncthreads();

    if (t < 300) {
        float a[8] = {0.f, 0.f, 0.f, 0.f, 0.f, 0.f, 0.f, 0.f};
        #pragma unroll 2
        for (int i = 0; i < 300; ++i) {
            float wm = Wm[i * 300 + t];
            #pragma unroll
            for (int r = 0; r < 8; ++r) a[r] += vnsS[r * 300 + i] * wm;
        }
        float bmt = bm[t];
        #pragma unroll
        for (int r = 0; r < 8; ++r)
            vmsS[r * 300 + t] = tanhf(a[r] + bmt);
    }
    __syncthreads();

    if (t < 24) {
        int r = t / 3, p = t % 3;
        float a = bd[p];
        for (int d = 0; d < 300; ++d) a += vmsS[r * 300 + d] * Wd[d * 3 + p];
        lg[t] = a;
    }
    __syncthreads();

    if (t < 8) {
        float l0 = lg[t * 3 + 0], l1 = lg[t * 3 + 1], l2 = lg[t * 3 + 2];
        float mx = fmaxf(l0, fmaxf(l1, l2));
        float e0 = expf(l0 - mx), e1 = expf(l1 - mx), e2 = expf(l2 - mx);
        float s = e0 + e1 + e2;
        out[(b0 + t) * 3 + 0] = e0 / s;
        out[(b0 + t) * 3 + 1] = e1 / s;
        out[(b0 + t) * 3 + 2] = e2 / s;
    }
}

extern "C" void kernel_launch(void* const* d_in, const int* in_sizes, int n_in,
                              void* d_out, int out_size, void* d_ws, size_t ws_size,
                              hipStream_t stream)
{
    (void)in_sizes; (void)n_in; (void)out_size; (void)ws_size;
    const int*   text   = (const int*)d_in[0];
    const int*   aspect = (const int*)d_in[1];
    const int*   left   = (const int*)d_in[2];
    const float* embed  = (const float*)d_in[3];
    const float* Wx     = (const float*)d_in[4];
    // d_in[5] = Ws : dead code in reference (s = v_s @ Ws is unused)
    const float* Wk     = (const float*)d_in[6];
    const float* bk     = (const float*)d_in[7];
    const float* Wq     = (const float*)d_in[8];
    const float* bq     = (const float*)d_in[9];
    const float* wmlp   = (const float*)d_in[10];
    const float* Wproj  = (const float*)d_in[11];
    const float* bproj  = (const float*)d_in[12];
    const float* Wm     = (const float*)d_in[13];
    const float* bm     = (const float*)d_in[14];
    const float* Wd     = (const float*)d_in[15];
    const float* bd     = (const float*)d_in[16];
    float* out = (float*)d_out;
    float* ws  = (float*)d_ws;

    hipLaunchKernelGGL(k_setup, dim3(301), dim3(320), 0, stream,
                       Wx, Wk, bk, Wq, bq, wmlp, Wproj, bproj, ws);
    hipLaunchKernelGGL(k_main, dim3(256), dim3(1024), 0, stream,
                       text, aspect, left, embed, ws);
    hipLaunchKernelGGL(k_tail, dim3(32), dim3(320), 0, stream,
                       Wm, bm, Wd, bd, out, ws);
}

// Round 2
// 245.066 us; speedup vs baseline: 1.9774x; 1.9774x over previous
//
#include <hip/hip_runtime.h>
#include <math.h>

// ws layout (float offsets)
#define WS_KV 0       // 300: Wk @ u           (16B aligned)
#define WS_C0 300     // bk . u
#define WS_C1 301     // bq . u2
#define WS_H0 304     // 300: h ping
#define WS_H1 604     // 300: h pong (final g lives here after 3 hops)
#define WS_MW 1024    // 256*300 softmax-weighted (w*emb) sums  (16B aligned)
#define WS_VS 77824   // 256*300 v_s vectors                    (16B aligned)

__device__ __forceinline__ float wred(float v) {
#pragma unroll
    for (int off = 32; off > 0; off >>= 1) v += __shfl_xor(v, off);
    return v;
}

// ---------------------------------------------------------------------------
// k_prep: grid 302 x 64. One wave per output — all loads issue in one round.
//  blocks 0..299: kv[j] = dot(Wk row j, u); h0[j] = dot(Wq row j, u2)
//  block 300: c0 = bk.u ; block 301: c1 = bq.u2
// ---------------------------------------------------------------------------
__global__ __launch_bounds__(64) void k_prep(
    const float* __restrict__ Wk, const float* __restrict__ bk,
    const float* __restrict__ Wq, const float* __restrict__ bq,
    const float* __restrict__ wmlp, float* __restrict__ ws)
{
    const int lane = threadIdx.x;
    const int j = blockIdx.x;
    const float* u  = wmlp;
    const float* u2 = wmlp + 300;
    if (j < 300) {
        float pk = 0.f, pq = 0.f;
#pragma unroll
        for (int k = 0; k < 5; ++k) {
            int idx = lane + 64 * k;
            if (idx < 300) {
                pk += Wk[j * 300 + idx] * u[idx];
                pq += Wq[j * 300 + idx] * u2[idx];
            }
        }
        pk = wred(pk); pq = wred(pq);
        if (lane == 0) { ws[WS_KV + j] = pk; ws[WS_H0 + j] = pq; }
    } else if (j == 300) {
        float p = 0.f;
#pragma unroll
        for (int k = 0; k < 5; ++k) { int idx = lane + 64 * k; if (idx < 300) p += bk[idx] * u[idx]; }
        p = wred(p);
        if (lane == 0) ws[WS_C0] = p;
    } else {
        float p = 0.f;
#pragma unroll
        for (int k = 0; k < 5; ++k) { int idx = lane + 64 * k; if (idx < 300) p += bq[idx] * u2[idx]; }
        p = wred(p);
        if (lane == 0) ws[WS_C1] = p;
    }
}

// ---------------------------------------------------------------------------
// k_hop: grid 300 x 64: dst[j] = dot(Wx row j, src). Launched 3x (ping-pong).
// ---------------------------------------------------------------------------
__global__ __launch_bounds__(64) void k_hop(
    const float* __restrict__ Wx, const float* __restrict__ src,
    float* __restrict__ dst)
{
    const int lane = threadIdx.x;
    const int j = blockIdx.x;
    float p = 0.f;
#pragma unroll
    for (int k = 0; k < 5; ++k) {
        int idx = lane + 64 * k;
        if (idx < 300) p += Wx[j * 300 + idx] * src[idx];
    }
    p = wred(p);
    if (lane == 0) dst[j] = p;
}

// ---------------------------------------------------------------------------
// k_main: grid 256 x 1024. One block per batch row; 16 waves x 32 tokens.
// float4 row loads (2/token), ILP-2 token pairs, single-pass exp-weighted sum.
// ---------------------------------------------------------------------------
__global__ __launch_bounds__(1024) void k_main(
    const int* __restrict__ text, const int* __restrict__ aspect,
    const int* __restrict__ left, const float* __restrict__ embed,
    float* __restrict__ ws)
{
    const int b = blockIdx.x;
    const int t = threadIdx.x;
    const int wv = t >> 6;
    const int lane = t & 63;

    __shared__ int   toks[512];
    __shared__ int   atoks[8];
    __shared__ float red[512];
    __shared__ __align__(16) float accW[16 * 300];
    __shared__ __align__(16) float vsW[16 * 300];
    __shared__ float denomW[16];
    __shared__ int   cnts[3];
    __shared__ float sc[4];

    if (t < 3) cnts[t] = 0;
    __syncthreads();

    bool predm = false, predl = false, preda = false;
    if (t < 512) { int tk = text[b * 512 + t]; toks[t] = tk; predm = (tk != 0); }
    else if (t < 576) predl = (left[b * 64 + (t - 512)] != 0);
    else if (t < 584) { int a = t - 576; int ak = aspect[b * 8 + a]; atoks[a] = ak; preda = (ak != 0); }
    {
        unsigned long long m;
        m = __ballot(predm); if (lane == 0 && m) atomicAdd(&cnts[0], __popcll(m));
        m = __ballot(predl); if (lane == 0 && m) atomicAdd(&cnts[1], __popcll(m));
        m = __ballot(preda); if (lane == 0 && m) atomicAdd(&cnts[2], __popcll(m));
    }
    __syncthreads();

    if (t < 300) {
        float s = 0.f;
#pragma unroll
        for (int a = 0; a < 8; ++a) s += embed[(size_t)atoks[a] * 300 + t];
        red[t] = (s / (float)cnts[2]) * ws[WS_H1 + t];   // g lives in H1
    } else if (t < 512) red[t] = 0.f;
    __syncthreads();
    for (int s = 256; s > 0; s >>= 1) { if (t < s) red[t] += red[t + s]; __syncthreads(); }
    if (t == 0) {
        sc[0] = (float)cnts[0];
        sc[1] = (float)(cnts[1] - cnts[2]);
        sc[2] = (float)cnts[1];
        sc[3] = red[0] + ws[WS_C0] + ws[WS_C1];
    }
    __syncthreads();
    const float mem_len_f = sc[0], startf = sc[1], endf = sc[2], qb = sc[3];

    const float4* kv4 = (const float4*)(ws + WS_KV);
    const float4* emb4 = (const float4*)embed;   // row = tok*75 float4s
    const bool hasB = (lane < 11);
    const float4 kva = kv4[lane];
    const float4 kvb = hasB ? kv4[64 + lane] : make_float4(0.f, 0.f, 0.f, 0.f);

    float4 accA = make_float4(0.f,0.f,0.f,0.f), accB = make_float4(0.f,0.f,0.f,0.f);
    float4 vsA  = make_float4(0.f,0.f,0.f,0.f), vsB  = make_float4(0.f,0.f,0.f,0.f);
    float denom = 0.f;

    for (int it = 0; it < 16; ++it) {
        const int l0 = wv * 32 + 2 * it, l1 = l0 + 1;
        const long r0 = (long)toks[l0] * 75, r1 = (long)toks[l1] * 75;
        float4 a0 = emb4[r0 + lane];
        float4 a1 = emb4[r1 + lane];
        float4 b0 = hasB ? emb4[r0 + 64 + lane] : make_float4(0.f,0.f,0.f,0.f);
        float4 b1 = hasB ? emb4[r1 + 64 + lane] : make_float4(0.f,0.f,0.f,0.f);

        float pd0 = a0.x*kva.x + a0.y*kva.y + a0.z*kva.z + a0.w*kva.w
                  + b0.x*kvb.x + b0.y*kvb.y + b0.z*kvb.z + b0.w*kvb.w;
        float pd1 = a1.x*kva.x + a1.y*kva.y + a1.z*kva.z + a1.w*kva.w
                  + b1.x*kvb.x + b1.y*kvb.y + b1.z*kvb.z + b1.w*kvb.w;
#pragma unroll
        for (int off = 32; off > 0; off >>= 1) {
            pd0 += __shfl_xor(pd0, off);
            pd1 += __shfl_xor(pd1, off);
        }

        const float f0 = (float)l0, f1 = (float)l1;
        float lv0 = (f0 < startf) ? (startf - f0) : ((f0 <= endf) ? 0.f : (f0 - endf));
        float lv1 = (f1 < startf) ? (startf - f1) : ((f1 <= endf) ? 0.f : (f1 - endf));
        float w0 = 1.f - lv0 / mem_len_f; w0 = (f0 < mem_len_f) ? w0 : 0.f;
        float w1 = 1.f - lv1 / mem_len_f; w1 = (f1 < mem_len_f) ? w1 : 0.f;

        const float p0 = expf(tanhf(w0 * pd0 + qb));
        const float p1 = expf(tanhf(w1 * pd1 + qb));
        const float pw0 = p0 * w0, pw1 = p1 * w1;

        accA.x += pw0*a0.x + pw1*a1.x;  accA.y += pw0*a0.y + pw1*a1.y;
        accA.z += pw0*a0.z + pw1*a1.z;  accA.w += pw0*a0.w + pw1*a1.w;
        accB.x += pw0*b0.x + pw1*b1.x;  accB.y += pw0*b0.y + pw1*b1.y;
        accB.z += pw0*b0.z + pw1*b1.z;  accB.w += pw0*b0.w + pw1*b1.w;
        vsA.x += a0.x + a1.x;  vsA.y += a0.y + a1.y;
        vsA.z += a0.z + a1.z;  vsA.w += a0.w + a1.w;
        vsB.x += b0.x + b1.x;  vsB.y += b0.y + b1.y;
        vsB.z += b0.z + b1.z;  vsB.w += b0.w + b1.w;
        denom += p0 + p1;
    }

    *(float4*)&accW[wv * 300 + 4 * lane] = accA;
    *(float4*)&vsW [wv * 300 + 4 * lane] = vsA;
    if (hasB) {
        *(float4*)&accW[wv * 300 + 256 + 4 * lane] = accB;
        *(float4*)&vsW [wv * 300 + 256 + 4 * lane] = vsB;
    }
    if (lane == 0) denomW[wv] = denom;
    __syncthreads();

    if (t < 300) {
        float ds = 0.f;
#pragma unroll
        for (int w = 0; w < 16; ++w) ds += denomW[w];
        float ms = 0.f, vs = 0.f;
#pragma unroll
        for (int w = 0; w < 16; ++w) { ms += accW[w * 300 + t]; vs += vsW[w * 300 + t]; }
        ws[WS_MW + b * 300 + t] = ms / ds;
        ws[WS_VS + b * 300 + t] = vs / mem_len_f;
    }
}

// ---------------------------------------------------------------------------
// k_tail: grid 256 x 960. One batch row per block; 3-way K-split per GEMM.
// t1 = mw@Wk + bk ; vns = t1@Wproj + bproj + v_s ; vms = tanh(vns@Wm + bm);
// out = softmax(vms@Wd + bd)
// ---------------------------------------------------------------------------
__global__ __launch_bounds__(960) void k_tail(
    const float* __restrict__ Wk, const float* __restrict__ bk,
    const float* __restrict__ Wproj, const float* __restrict__ bproj,
    const float* __restrict__ Wm, const float* __restrict__ bm,
    const float* __restrict__ Wd, const float* __restrict__ bd,
    float* __restrict__ out, const float* __restrict__ ws)
{
    const int t = threadIdx.x;
    const int b = blockIdx.x;
    const int seg = t / 320;      // 0..2 (K-split)
    const int j = t - seg * 320;  // 0..319 (output col)

    __shared__ float A[300], T[300], part[900], vms[300], lg[3];

    if (t < 300) A[t] = ws[WS_MW + b * 300 + t];
    __syncthreads();

    // GEMM1: T = A @ Wk + bk
    if (j < 300) {
        const int k0 = seg * 100;
        float acc = 0.f;
#pragma unroll 10
        for (int i = 0; i < 100; ++i) acc += A[k0 + i] * Wk[(k0 + i) * 300 + j];
        part[seg * 300 + j] = acc;
    }
    __syncthreads();
    if (t < 300) T[t] = part[t] + part[300 + t] + part[600 + t] + bk[t];
    __syncthreads();

    // GEMM2: A = T @ Wproj + bproj + v_s
    if (j < 300) {
        const int k0 = seg * 100;
        float acc = 0.f;
#pragma unroll 10
        for (int i = 0; i < 100; ++i) acc += T[k0 + i] * Wproj[(k0 + i) * 300 + j];
        part[seg * 300 + j] = acc;
    }
    __syncthreads();
    if (t < 300) A[t] = part[t] + part[300 + t] + part[600 + t] + bproj[t] + ws[WS_VS + b * 300 + t];
    __syncthreads();

    // GEMM3: vms = tanh(A @ Wm + bm)
    if (j < 300) {
        const int k0 = seg * 100;
        float acc = 0.f;
#pragma unroll 10
        for (int i = 0; i < 100; ++i) acc += A[k0 + i] * Wm[(k0 + i) * 300 + j];
        part[seg * 300 + j] = acc;
    }
    __syncthreads();
    if (t < 300) vms[t] = tanhf(part[t] + part[300 + t] + part[600 + t] + bm[t]);
    __syncthreads();

    // logits: waves 0..2 each handle one class p
    const int wv = t >> 6, lane = t & 63;
    if (wv < 3) {
        float p = 0.f;
#pragma unroll
        for (int k = 0; k < 5; ++k) { int d = lane + 64 * k; if (d < 300) p += vms[d] * Wd[d * 3 + wv]; }
        p = wred(p);
        if (lane == 0) lg[wv] = p + bd[wv];
    }
    __syncthreads();
    if (t == 0) {
        float l0 = lg[0], l1 = lg[1], l2 = lg[2];
        float mx = fmaxf(l0, fmaxf(l1, l2));
        float e0 = expf(l0 - mx), e1 = expf(l1 - mx), e2 = expf(l2 - mx);
        float s = e0 + e1 + e2;
        out[b * 3 + 0] = e0 / s;
        out[b * 3 + 1] = e1 / s;
        out[b * 3 + 2] = e2 / s;
    }
}

extern "C" void kernel_launch(void* const* d_in, const int* in_sizes, int n_in,
                              void* d_out, int out_size, void* d_ws, size_t ws_size,
                              hipStream_t stream)
{
    (void)in_sizes; (void)n_in; (void)out_size; (void)ws_size;
    const int*   text   = (const int*)d_in[0];
    const int*   aspect = (const int*)d_in[1];
    const int*   left   = (const int*)d_in[2];
    const float* embed  = (const float*)d_in[3];
    const float* Wx     = (const float*)d_in[4];
    // d_in[5] = Ws : dead code in reference
    const float* Wk     = (const float*)d_in[6];
    const float* bk     = (const float*)d_in[7];
    const float* Wq     = (const float*)d_in[8];
    const float* bq     = (const float*)d_in[9];
    const float* wmlp   = (const float*)d_in[10];
    const float* Wproj  = (const float*)d_in[11];
    const float* bproj  = (const float*)d_in[12];
    const float* Wm     = (const float*)d_in[13];
    const float* bm     = (const float*)d_in[14];
    const float* Wd     = (const float*)d_in[15];
    const float* bd     = (const float*)d_in[16];
    float* out = (float*)d_out;
    float* ws  = (float*)d_ws;

    hipLaunchKernelGGL(k_prep, dim3(302), dim3(64), 0, stream, Wk, bk, Wq, bq, wmlp, ws);
    hipLaunchKernelGGL(k_hop, dim3(300), dim3(64), 0, stream, Wx, ws + WS_H0, ws + WS_H1);
    hipLaunchKernelGGL(k_hop, dim3(300), dim3(64), 0, stream, Wx, ws + WS_H1, ws + WS_H0);
    hipLaunchKernelGGL(k_hop, dim3(300), dim3(64), 0, stream, Wx, ws + WS_H0, ws + WS_H1);
    hipLaunchKernelGGL(k_main, dim3(256), dim3(1024), 0, stream, text, aspect, left, embed, ws);
    hipLaunchKernelGGL(k_tail, dim3(256), dim3(960), 0, stream,
                       Wk, bk, Wproj, bproj, Wm, bm, Wd, bd, out, ws);
}